// Round 1
// baseline (237.466 us; speedup 1.0000x reference)
//
#include <hip/hip_runtime.h>
#include <stdint.h>

// ---------- bf16 helpers (storage = unsigned short) ----------
__device__ __forceinline__ float b2f(unsigned short u) {
    union { uint32_t i; float f; } v; v.i = ((uint32_t)u) << 16; return v.f;
}
__device__ __forceinline__ unsigned short f2b(float f) {
    union { float f; uint32_t i; } v; v.f = f;
    uint32_t r = v.i + 0x7fffu + ((v.i >> 16) & 1u);   // RNE
    return (unsigned short)(r >> 16);
}

typedef __bf16 bf16x8 __attribute__((ext_vector_type(8)));
typedef float  f32x16 __attribute__((ext_vector_type(16)));

// ---------------------------------------------------------------------------
// cvt: xb = bf16(x), 8 elems/thread.
// ---------------------------------------------------------------------------
__global__ __launch_bounds__(256)
void cvt_f32_bf16(const float* __restrict__ x, unsigned short* __restrict__ xb) {
    int t = blockIdx.x * 256 + threadIdx.x;
    const float4* p = (const float4*)(x + (size_t)t * 8);
    float4 f0 = p[0], f1 = p[1];
    int4 o;
    o.x = (uint32_t)f2b(f0.x) | ((uint32_t)f2b(f0.y) << 16);
    o.y = (uint32_t)f2b(f0.z) | ((uint32_t)f2b(f0.w) << 16);
    o.z = (uint32_t)f2b(f1.x) | ((uint32_t)f2b(f1.y) << 16);
    o.w = (uint32_t)f2b(f1.z) | ((uint32_t)f2b(f1.w) << 16);
    ((int4*)xb)[t] = o;
}

// ---------------------------------------------------------------------------
// build_T: T[rm=(r1*16+n2)*16+m2][n3][m3] = sum_r2 c1[rm][r2]*c2[(r2*N3+n3)*M3+m3]
// ---------------------------------------------------------------------------
template<int N3, int M3>
__global__ void build_T(const float* __restrict__ c1,
                        const float* __restrict__ c2,
                        float* __restrict__ T) {
    int e = blockIdx.x * 256 + threadIdx.x;
    int m3 = e % M3;
    int t  = e / M3;
    int n3 = t % N3;
    int rm = t / N3;
    float s = 0.f;
#pragma unroll
    for (int r2 = 0; r2 < 16; ++r2)
        s += c1[rm * 16 + r2] * c2[(r2 * N3 + n3) * M3 + m3];
    T[e] = s;
}

// ---------------------------------------------------------------------------
// build_W (coalesced remap): thread t = (((n1*M1+m1)*N2+n2)*M2+m2)*M3+m3.
// ---------------------------------------------------------------------------
template<int N1, int N2, int N3, int M1, int M2, int M3>
__global__ __launch_bounds__(256)
void build_W(const float* __restrict__ c0,
             const float* __restrict__ T,
             unsigned short* __restrict__ W) {
    constexpr int K = N1 * N2 * N3;
    int t  = blockIdx.x * 256 + threadIdx.x;
    int m3 = t % M3;
    int m2 = (t / M3) % M2;
    int n2 = (t / (M3 * M2)) % N2;
    int m1 = (t / (M3 * M2 * N2)) % M1;
    int n1 =  t / (M3 * M2 * N2 * M1);

    float c0r[16];
    const float4* c0p = (const float4*)(c0 + (n1 * M1 + m1) * 16);
#pragma unroll
    for (int i = 0; i < 4; ++i) ((float4*)c0r)[i] = c0p[i];

    float acc[N3] = {};
#pragma unroll
    for (int r1 = 0; r1 < 16; ++r1) {
        const float* Tp = T + (size_t)(((r1 * 16 + n2) * 16 + m2) * N3) * M3 + m3;
#pragma unroll
        for (int n3 = 0; n3 < N3; ++n3)
            acc[n3] += c0r[r1] * Tp[n3 * M3];
    }

    unsigned short ob[N3];
#pragma unroll
    for (int n3 = 0; n3 < N3; ++n3) ob[n3] = f2b(acc[n3]);

    unsigned short* dst = W + (size_t)((m1 * M2 + m2) * M3 + m3) * K
                            + (n1 * N2 + n2) * N3;
#pragma unroll
    for (int c = 0; c < N3 / 8; ++c)
        ((int4*)dst)[c] = ((const int4*)ob)[c];
}

// ---------------------------------------------------------------------------
// gemm3p: 3-buffer counted-vmcnt pipelined GEMM.  C[M][NCOLS] = A*Bt^T + bias.
//
// All 8 waves compute (no producer split).  K-tiles of BK=64 are staged with
// global_load_lds (width 16) into a TRIPLE-buffered LDS ring: tile t+2 is
// staged during tile t's phases into the buffer freed at end of tile t-1
// (race-free at tile granularity: buffer (t+2)%3 was last read at the
// end-of-tile-(t-1) barrier).  End-of-tile sync is s_waitcnt vmcnt(LPT):
// exactly tile t+2's LPT loads may remain in flight, so tile t+1 is landed
// -- loads are never drained to 0 in the main loop (T3+T4, m218).
//
// LDS layout per operand tile: [rows][64] bf16, 128B row, with XOR swizzle
// chunk^=(row&7) (T2/G4).  global_load_lds writes linearly, so the swizzle
// is applied by inverse-permuting the per-lane GLOBAL source (rule 21) and
// re-applied on the ds_read address; ds_read_b128 fragment reads are then
// bank-conflict-free (16 rows x same chunk -> 8 distinct bank quads x2).
//
// Phases: {ds_read frags | issue stage chunks -> s_barrier -> lgkmcnt(0) ->
// setprio(1) -> 8x mfma_32x32x16_bf16 -> setprio(0) [-> vmcnt(LPT)] ->
// s_barrier}.  "memory"-clobbered asm adjacent to every raw barrier stops
// the compiler hoisting LDS reads / stage issues across the sync.
//
// C/D mapping (m74/m101, same as prior working kernel):
//   col = lane&31, row = (reg&3)+8*(reg>>2)+4*(lane>>5).
// XCD-chunked bijective block swizzle (nwg%8==0 for both grids).
// 1 block/CU (dynamic LDS 144KB / 96KB) -- global_load_lds safe (<=4/CU).
// ---------------------------------------------------------------------------
template<int BM, int BN>
__device__ __forceinline__ void stage_chunk16(
    const unsigned short* __restrict__ A,
    const unsigned short* __restrict__ Bt,
    char* __restrict__ dstbuf, int ktot,
    int rowBase, int colBase, int tk, int c, int tid)
{
    const int off  = (c * 512 + tid) * 16;          // linear byte off in tile
    const bool isB = off >= BM * 128;
    const int off2 = isB ? off - BM * 128 : off;
    const int r    = off2 >> 7;                     // row within tile
    const int jg   = ((off2 >> 4) & 7) ^ (r & 7);   // inverse-swizzled chunk
    const unsigned short* src = (isB ? Bt + (size_t)(colBase + r) * ktot
                                     : A  + (size_t)(rowBase + r) * ktot)
                                + tk * 64 + jg * 8;
    // wave-uniform LDS dest; HW adds lane*16
    void* dst = dstbuf + (c * 8192 + (tid >> 6) * 1024);
    __builtin_amdgcn_global_load_lds(
        (const __attribute__((address_space(1))) void*)src,
        (__attribute__((address_space(3))) void*)dst, 16, 0, 0);
}

template<int BM, int BN, int KTOT, int NCOLS, int PPT, bool DO_GELU, bool C_F32>
__global__ __launch_bounds__(512, 2)
void gemm3p(const unsigned short* __restrict__ A,
            const unsigned short* __restrict__ Bt,
            const float* __restrict__ bias,
            void* __restrict__ Cv)
{
    constexpr int BK   = 64;
    constexpr int NT   = KTOT / BK;
    constexpr int BUFB = (BM + BN) * 128;                // bytes per buffer
    constexpr int LPT  = (BM + BN) * BK * 2 / (512 * 16);// loads/thread/tile
    constexpr int SPP  = LPT / PPT;                      // stage issues/phase
    constexpr int KPP  = 4 / PPT;                        // k16 steps/phase
    constexpr int WGM  = 4, WGN = 2;                     // 8-wave grid
    constexpr int FI   = BM / (WGM * 32);
    constexpr int FJ   = BN / (WGN * 32);
    constexpr int GX   = NCOLS / BN;

    extern __shared__ char smem[];

    const int tid  = threadIdx.x;
    const int lane = tid & 63;
    const int wave = tid >> 6;
    const int m32  = lane & 31;
    const int kh   = lane >> 5;
    const int wm   = wave >> 1;
    const int wn   = wave & 1;

    // XCD-chunked bijective swizzle (nwg % 8 == 0 for our grids)
    int lin = blockIdx.y * GX + blockIdx.x;
    const int cpx = (int)(GX * gridDim.y) >> 3;
    lin = (lin & 7) * cpx + (lin >> 3);
    const int rowBase = (lin / GX) * BM;
    const int colBase = (lin % GX) * BN;

    f32x16 acc[FI][FJ] = {};

    // ---- prologue: stage tiles 0,1 into buffers 0,1
#pragma unroll
    for (int c = 0; c < LPT; ++c)
        stage_chunk16<BM, BN>(A, Bt, smem, KTOT, rowBase, colBase, 0, c, tid);
#pragma unroll
    for (int c = 0; c < LPT; ++c)
        stage_chunk16<BM, BN>(A, Bt, smem + BUFB, KTOT, rowBase, colBase, 1, c, tid);
    asm volatile("s_waitcnt vmcnt(%0)" :: "n"(LPT) : "memory");   // tile 0 landed
    __builtin_amdgcn_s_barrier();
    asm volatile("" ::: "memory");

    int bt = 0;                                   // t % 3
    for (int t = 0; t < NT; ++t) {
        const int sb = bt >= 1 ? bt - 1 : 2;      // (bt+2)%3
        const char* Ab = smem + bt * BUFB;
        const char* Bb = Ab + BM * 128;
        char* Sb = smem + sb * BUFB;
        const bool doStage = (t + 2 < NT);

#pragma unroll
        for (int ph = 0; ph < PPT; ++ph) {
            // --- ds_read fragments for this phase's k16 steps
            bf16x8 af[FI][KPP], bfr[FJ][KPP];
#pragma unroll
            for (int i = 0; i < FI; ++i) {
                const int rr = wm * (BM / WGM) + i * 32 + m32;
#pragma unroll
                for (int u = 0; u < KPP; ++u) {
                    const int lc = (ph * KPP + u) * 2 + kh;
                    af[i][u] = *(const bf16x8*)(Ab + rr * 128 + ((lc ^ (rr & 7)) << 4));
                }
            }
#pragma unroll
            for (int j = 0; j < FJ; ++j) {
                const int rr = wn * (BN / WGN) + j * 32 + m32;
#pragma unroll
                for (int u = 0; u < KPP; ++u) {
                    const int lc = (ph * KPP + u) * 2 + kh;
                    bfr[j][u] = *(const bf16x8*)(Bb + rr * 128 + ((lc ^ (rr & 7)) << 4));
                }
            }
            // --- issue async stage of tile t+2 (lands >= 1 tile later)
            if (doStage) {
#pragma unroll
                for (int c = 0; c < SPP; ++c)
                    stage_chunk16<BM, BN>(A, Bt, Sb, KTOT, rowBase, colBase,
                                          t + 2, ph * SPP + c, tid);
            }
            __builtin_amdgcn_s_barrier();
            asm volatile("s_waitcnt lgkmcnt(0)" ::: "memory");
            __builtin_amdgcn_s_setprio(1);
#pragma unroll
            for (int u = 0; u < KPP; ++u)
#pragma unroll
                for (int i = 0; i < FI; ++i)
#pragma unroll
                    for (int j = 0; j < FJ; ++j)
                        acc[i][j] = __builtin_amdgcn_mfma_f32_32x32x16_bf16(
                            af[i][u], bfr[j][u], acc[i][j], 0, 0, 0);
            __builtin_amdgcn_s_setprio(0);
            if (ph == PPT - 1) {
                if (t + 2 < NT) {
                    // counted: only tile t+2's LPT loads may remain in flight
                    asm volatile("s_waitcnt vmcnt(%0)" :: "n"(LPT) : "memory");
                } else if (t + 1 < NT) {
                    // epilogue drain: nothing staged this tile
                    asm volatile("s_waitcnt vmcnt(0)" ::: "memory");
                }
            }
            __builtin_amdgcn_s_barrier();
            asm volatile("" ::: "memory");
        }
        bt = bt < 2 ? bt + 1 : 0;
    }

    // ---- epilogue: col=lane&31, row=(reg&3)+8*(reg>>2)+4*(lane>>5)
    const int waveM = wm * (BM / WGM);
    const int waveN = wn * (BN / WGN);
#pragma unroll
    for (int i = 0; i < FI; ++i) {
#pragma unroll
        for (int j = 0; j < FJ; ++j) {
            const int col = colBase + waveN + j * 32 + m32;
            const float bv = bias[col];
#pragma unroll
            for (int reg = 0; reg < 16; ++reg) {
                const int row = rowBase + waveM + i * 32 +
                                (reg & 3) + 8 * (reg >> 2) + 4 * kh;
                float z = acc[i][j][reg] + bv;
                if (DO_GELU)
                    z = 0.5f * z * (1.f + erff(z * 0.70710678118654752f));
                const size_t off = (size_t)row * NCOLS + col;
                if (C_F32) ((float*)Cv)[off] = z;
                else       ((unsigned short*)Cv)[off] = f2b(z);
            }
        }
    }
}

// ---------------------------------------------------------------------------
// OLD producer-consumer GEMM -- kept ONLY for the small-workspace fallback
// (fp32 A without a bf16 scratch copy).  Unchanged from the verified kernel.
// ---------------------------------------------------------------------------
#define PC_COMPUTE(BUF)                                                       \
    {                                                                         \
        _Pragma("unroll")                                                     \
        for (int ks = 0; ks < 4; ++ks) {                                      \
            bf16x8 a_f[FI], b_f[FJ];                                          \
            _Pragma("unroll")                                                 \
            for (int i = 0; i < FI; ++i) {                                    \
                const int key = (m32 & 7) ^                                   \
                    (((waveM >> 3) + 4 * i + (m32 >> 3)) & 7);                \
                const int slot = ((ks * 2 + khalf) ^ key) * 8;                \
                a_f[i] = *(const bf16x8*)&As[(BUF) * ASZ +                    \
                          (waveM + i * 32 + m32) * BK + slot];                \
            }                                                                 \
            _Pragma("unroll")                                                 \
            for (int j = 0; j < FJ; ++j) {                                    \
                const int key = (m32 & 7) ^                                   \
                    (((waveN >> 3) + 4 * j + (m32 >> 3)) & 7);                \
                const int slot = ((ks * 2 + khalf) ^ key) * 8;                \
                b_f[j] = *(const bf16x8*)&Bs[(BUF) * BSZ +                    \
                          (waveN + j * 32 + m32) * BK + slot];                \
            }                                                                 \
            _Pragma("unroll")                                                 \
            for (int i = 0; i < FI; ++i)                                      \
                _Pragma("unroll")                                             \
                for (int j = 0; j < FJ; ++j)                                  \
                    acc[i][j] = __builtin_amdgcn_mfma_f32_32x32x16_bf16(      \
                        a_f[i], b_f[j], acc[i][j], 0, 0, 0);                  \
        }                                                                     \
    }

template<int BM, int BN, int KTOT, bool DO_GELU, bool A_F32, bool C_F32>
__global__ __launch_bounds__(512, 4)
void gemm_pc(const void* __restrict__ Av,
             const unsigned short* __restrict__ Bt,
             const float* __restrict__ bias,
             void* __restrict__ Cv,
             int Ncols) {
    constexpr int BK  = 64;
    constexpr int CA  = BM / 8;
    constexpr int CB  = BN / 8;
    constexpr int PA  = CA / 4;
    constexpr int PB  = CB / 4;
    constexpr int FI  = BM / 64;
    constexpr int FJ  = BN / 64;
    constexpr int ASZ = BM * BK;
    constexpr int BSZ = BN * BK;
    __shared__ unsigned short As[2 * ASZ];
    __shared__ unsigned short Bs[2 * BSZ];

    const int tid  = threadIdx.x;
    const int lane = tid & 63;
    const int wave = tid >> 6;
    const int rowBase = blockIdx.y * BM;
    const int colBase = blockIdx.x * BN;

    const int lr    = lane >> 3;
    const int jj    = lane & 7;
    const int m32   = lane & 31;
    const int khalf = lane >> 5;

    if (wave >= 4) {
        const int pw = wave - 4;
#pragma unroll
        for (int it = 0; it < PA; ++it) {
            const int c  = pw * PA + it;
            const int jg = jj ^ lr ^ (c & 7);
            const size_t aoff = (size_t)(rowBase + c * 8 + lr) * KTOT + jg * 8;
            int4 v;
            if (A_F32) {
                const float* ga = (const float*)Av + aoff;
                float4 f0 = *(const float4*)ga;
                float4 f1 = *(const float4*)(ga + 4);
                v.x = (uint32_t)f2b(f0.x) | ((uint32_t)f2b(f0.y) << 16);
                v.y = (uint32_t)f2b(f0.z) | ((uint32_t)f2b(f0.w) << 16);
                v.z = (uint32_t)f2b(f1.x) | ((uint32_t)f2b(f1.y) << 16);
                v.w = (uint32_t)f2b(f1.z) | ((uint32_t)f2b(f1.w) << 16);
            } else {
                v = *(const int4*)((const unsigned short*)Av + aoff);
            }
            *(int4*)&As[c * 512 + lane * 8] = v;
        }
#pragma unroll
        for (int it = 0; it < PB; ++it) {
            const int c  = pw * PB + it;
            const int jg = jj ^ lr ^ (c & 7);
            *(int4*)&Bs[c * 512 + lane * 8] =
                *(const int4*)(Bt + (size_t)(colBase + c * 8 + lr) * KTOT + jg * 8);
        }
        __syncthreads();

        int buf = 1;
        for (int k0 = BK; k0 < KTOT; k0 += BK) {
            int4 aR[PA], bR[PB];
#pragma unroll
            for (int it = 0; it < PA; ++it) {
                const int c  = pw * PA + it;
                const int jg = jj ^ lr ^ (c & 7);
                const size_t aoff = (size_t)(rowBase + c * 8 + lr) * KTOT + k0 + jg * 8;
                if (A_F32) {
                    const float* ga = (const float*)Av + aoff;
                    float4 f0 = *(const float4*)ga;
                    float4 f1 = *(const float4*)(ga + 4);
                    int4 v;
                    v.x = (uint32_t)f2b(f0.x) | ((uint32_t)f2b(f0.y) << 16);
                    v.y = (uint32_t)f2b(f0.z) | ((uint32_t)f2b(f0.w) << 16);
                    v.z = (uint32_t)f2b(f1.x) | ((uint32_t)f2b(f1.y) << 16);
                    v.w = (uint32_t)f2b(f1.z) | ((uint32_t)f2b(f1.w) << 16);
                    aR[it] = v;
                } else {
                    aR[it] = *(const int4*)((const unsigned short*)Av + aoff);
                }
            }
#pragma unroll
            for (int it = 0; it < PB; ++it) {
                const int c  = pw * PB + it;
                const int jg = jj ^ lr ^ (c & 7);
                bR[it] = *(const int4*)(Bt + (size_t)(colBase + c * 8 + lr) * KTOT + k0 + jg * 8);
            }
#pragma unroll
            for (int it = 0; it < PA; ++it) {
                const int c = pw * PA + it;
                *(int4*)&As[buf * ASZ + c * 512 + lane * 8] = aR[it];
            }
#pragma unroll
            for (int it = 0; it < PB; ++it) {
                const int c = pw * PB + it;
                *(int4*)&Bs[buf * BSZ + c * 512 + lane * 8] = bR[it];
            }
            __syncthreads();
            buf ^= 1;
        }
    } else {
        const int waveM = (wave >> 1) * (BM / 2);
        const int waveN = (wave & 1) * (BN / 2);
        f32x16 acc[FI][FJ] = {};

        __syncthreads();

        int cur = 0;
        for (int k0 = BK; k0 < KTOT; k0 += BK) {
            PC_COMPUTE(cur)
            __syncthreads();
            cur ^= 1;
        }
        PC_COMPUTE(cur)

#pragma unroll
        for (int i = 0; i < FI; ++i) {
#pragma unroll
            for (int j = 0; j < FJ; ++j) {
                const int col = colBase + waveN + j * 32 + m32;
                const float bv = bias[col];
#pragma unroll
                for (int reg = 0; reg < 16; ++reg) {
                    const int row = rowBase + waveM + i * 32 +
                                    (reg & 3) + 8 * (reg >> 2) + 4 * khalf;
                    float z = acc[i][j][reg] + bv;
                    if (DO_GELU)
                        z = 0.5f * z * (1.f + erff(z * 0.70710678118654752f));
                    const size_t off = (size_t)row * Ncols + col;
                    if (C_F32) ((float*)Cv)[off] = z;
                    else       ((unsigned short*)Cv)[off] = f2b(z);
                }
            }
        }
    }
}

// ---------------------------------------------------------------------------
extern "C" void kernel_launch(void* const* d_in, const int* in_sizes, int n_in,
                              void* d_out, int out_size, void* d_ws, size_t ws_size,
                              hipStream_t stream) {
    const float* x      = (const float*)d_in[0];   // [4096,1024] fp32
    const float* fc1_c0 = (const float*)d_in[1];
    const float* fc1_c1 = (const float*)d_in[2];
    const float* fc1_c2 = (const float*)d_in[3];
    const float* fc1_b  = (const float*)d_in[4];
    const float* fc2_c0 = (const float*)d_in[5];
    const float* fc2_c1 = (const float*)d_in[6];
    const float* fc2_c2 = (const float*)d_in[7];
    const float* fc2_b  = (const float*)d_in[8];

    // Workspace layout (50 MB preferred):
    //   [0,8M)   W    bf16 -- W1t [4096][1024], later W2t [1024][4096]
    //   [8,10M)  T    f32 scratch
    //   [10,18M) xb   bf16 copy of x
    //   [18,50M) h    bf16 [4096][4096]
    char* ws = (char*)d_ws;
    unsigned short* W  = (unsigned short*)(ws);
    float*          T  = (float*)(ws + (8u << 20));
    const bool big = ws_size >= (50ull << 20);
    unsigned short* xb = (unsigned short*)(ws + (10u << 20));
    unsigned short* h  = (unsigned short*)(ws + (big ? (18u << 20) : (10u << 20)));

    // Dynamic-LDS opt-in (>64KB).  Non-stream metadata call: graph-capture safe.
    static bool attr_done = false;
    if (!attr_done) {
        attr_done = true;
        (void)hipFuncSetAttribute(
            reinterpret_cast<const void*>(&gemm3p<256, 128, 1024, 4096, 2, true, false>),
            hipFuncAttributeMaxDynamicSharedMemorySize, 3 * (256 + 128) * 128);
        (void)hipFuncSetAttribute(
            reinterpret_cast<const void*>(&gemm3p<128, 128, 4096, 1024, 1, false, true>),
            hipFuncAttributeMaxDynamicSharedMemorySize, 3 * (128 + 128) * 128);
    }

    // ---- layer 1: in (8,16,8) -> out (16,16,16)
    build_T<8, 16><<<2048, 256, 0, stream>>>(fc1_c1, fc1_c2, T);
    build_W<8, 16, 8, 16, 16, 16><<<2048, 256, 0, stream>>>(fc1_c0, T, W);
    if (big) {
        cvt_f32_bf16<<<2048, 256, 0, stream>>>(x, xb);
        // GEMM1: 256x128 tile, grid 32x16 = 512 blocks, 144KB LDS, 1 block/CU
        gemm3p<256, 128, 1024, 4096, 2, true, false>
            <<<dim3(32, 16), 512, 3 * (256 + 128) * 128, stream>>>(xb, W, fc1_b, h);
    } else {
        gemm_pc<128, 128, 1024, true, true, false>
            <<<dim3(32, 32), 512, 0, stream>>>(x, W, fc1_b, h, 4096);
    }

    // ---- layer 2: in (16,16,16) -> out (8,16,8)
    build_T<16, 8><<<2048, 256, 0, stream>>>(fc2_c1, fc2_c2, T);
    build_W<16, 16, 16, 8, 16, 8><<<1024, 256, 0, stream>>>(fc2_c0, T, W);
    // GEMM2: 128x128 tile, grid 8x32 = 256 blocks, 96KB LDS, 1 block/CU
    gemm3p<128, 128, 4096, 1024, 1, false, true>
        <<<dim3(8, 32), 512, 3 * (128 + 128) * 128, stream>>>(h, W, fc2_b, d_out);
}